// Round 12
// baseline (175.549 us; speedup 1.0000x reference)
//
#include <hip/hip_runtime.h>
#include <math.h>

#define EMBED   64
#define HIDDEN  256
#define SEQ     200
#define SEQP    208          // padded to 13 s-tiles of 16
#define MT      13
#define VOCAB   100000

typedef _Float16 f16x8  __attribute__((ext_vector_type(8)));
typedef _Float16 f16x2  __attribute__((ext_vector_type(2)));
typedef float    f32x4  __attribute__((ext_vector_type(4)));
typedef float    f32x2  __attribute__((ext_vector_type(2)));

// ---------------- ws layout ----------------
// [0   , 32K ) fragW16: f16 16*(W0+W2)  [tile 16][kc 2][lane 64] x f16x8
// [32K , 64K ) fragW3 : f16 16*W3       [tile 16][kc 2][lane 64] x f16x8
// [64K , 96K ) fragDt : f16 (W1-W2)^T   [tile 16][kc 2][lane 64] x f16x8
// [96K , 160K) fragB2 : f16 mlp_w1      [tile 16][kc 4][lane 64] x f16x8
// [160K, 160K+6.4M) emb8: fp8(16*user_emb), 64 B/vocab row (L3-resident)
//
// SESSION LEDGER:
//  - R18/R21 verified: 74 us fused / 165 us total. VALU 54 / MFMA 19 / occ 37.
//  - Register wall: >~60 arch-VGPRs of cross-phase state spills (WRITE_SIZE canary).
//  - Occupancy not the lever (53% == 37% == ~74 us). ws re-poisoned per launch.
//  - Grid-wide single-line atomics ~100 us. fp8 A-frags (8B) beat f16 (16B) on regs.
//  - R22 hypothesis: ~34 us of SIMD-idle = barrier convoys (9/row); amortize
//    them over 2 WAVE-DISJOINT rows per block (no cross-row reg state).
//  - R11 bench attempt: container infra failure (no data); resubmitting verbatim.

__global__ void din_setup(const float* __restrict__ attn_w1,
                          const float* __restrict__ mlp_w1,
                          const float* __restrict__ user_emb,
                          _Float16* __restrict__ fragW16,
                          _Float16* __restrict__ fragW3,
                          _Float16* __restrict__ fragDt,
                          _Float16* __restrict__ fragB2,
                          unsigned char* __restrict__ emb8,
                          int do_emb) {
  const int gid = blockIdx.x * 256 + threadIdx.x;
  if (gid < 2048) {                                 // fragW16: f16 16*(W0+W2)
    const int i = gid >> 7, rem = gid & 127, kc = rem >> 6, lane = rem & 63;
    const int n = i * 16 + (lane & 15);
    const int kb = kc * 32 + (lane >> 4) * 8;
    #pragma unroll
    for (int j = 0; j < 8; ++j)
      fragW16[gid * 8 + j] = (_Float16)(16.0f * (attn_w1[(kb + j) * HIDDEN + n]
                                               + attn_w1[(128 + kb + j) * HIDDEN + n]));
  } else if (gid < 4096) {                          // fragW3: f16 16*W3
    const int g = gid - 2048;
    const int i = g >> 7, rem = g & 127, kc = rem >> 6, lane = rem & 63;
    const int n = i * 16 + (lane & 15);
    const int kb = kc * 32 + (lane >> 4) * 8;
    #pragma unroll
    for (int j = 0; j < 8; ++j)
      fragW3[g * 8 + j] = (_Float16)(16.0f * attn_w1[(192 + kb + j) * HIDDEN + n]);
  } else if (gid < 6144) {                          // fragDt: f16 (W1-W2)^T A-frags
    const int g = gid - 4096;
    const int i = g >> 7, rem = g & 127, kc = rem >> 6, lane = rem & 63;
    const int n = i * 16 + (lane & 15);
    const int kb = kc * 32 + (lane >> 4) * 8;
    #pragma unroll
    for (int j = 0; j < 8; ++j)
      fragDt[g * 8 + j] = (_Float16)(attn_w1[(64 + kb + j) * HIDDEN + n]
                                   - attn_w1[(128 + kb + j) * HIDDEN + n]);
  } else if (gid < 10240) {                         // fragB2: mlp_w1 f16 A-frags
    const int g = gid - 6144;
    const int nt = g >> 8, kc = (g >> 6) & 3, lane = g & 63;
    const int n = nt * 16 + (lane & 15);
    const int kb = kc * 32 + (lane >> 4) * 8;
    #pragma unroll
    for (int j = 0; j < 8; ++j)
      fragB2[g * 8 + j] = (_Float16)mlp_w1[(kb + j) * HIDDEN + n];
  } else if (do_emb) {                              // emb8: fp8(16*user_emb)
    const int g = gid - 10240;                      // [0, 800000)
    if (g < VOCAB * EMBED / 8) {
      const int base = g * 8;
      const float4 x = *reinterpret_cast<const float4*>(&user_emb[base]);
      const float4 y = *reinterpret_cast<const float4*>(&user_emb[base + 4]);
      int lo = __builtin_amdgcn_cvt_pk_fp8_f32(16.f * x.x, 16.f * x.y, 0, false);
      lo     = __builtin_amdgcn_cvt_pk_fp8_f32(16.f * x.z, 16.f * x.w, lo, true);
      int hi = __builtin_amdgcn_cvt_pk_fp8_f32(16.f * y.x, 16.f * y.y, 0, false);
      hi     = __builtin_amdgcn_cvt_pk_fp8_f32(16.f * y.z, 16.f * y.w, hi, true);
      *reinterpret_cast<uint2*>(&emb8[base]) = uint2{(unsigned)lo, (unsigned)hi};
    }
  }
}

// ---------------- fused kernel: one block (256 thr) per TWO rows, wave-disjoint ----------------
// waves 0-1 -> row A, waves 2-3 -> row B. Each wave: 8 n-tiles in 2 sequential
// groups of 4 (R18's proven 60-VGPR group pipeline, recomputed per group; logit
// accumulation across groups through LDS f32 as in R15). No cross-row register
// state. 9 barriers per 2 rows (was 9 per row).
// Canary: WRITE_SIZE >= 1 MB => spilled => revert to R21.
__global__ __launch_bounds__(256, 4)
void din_fused_kernel(const int* __restrict__ user_hist,
                      const int* __restrict__ target_item,
                      const float* __restrict__ user_emb,
                      const float* __restrict__ item_emb,
                      const float* __restrict__ attn_b1,
                      const float* __restrict__ attn_w2,
                      const float* __restrict__ mlp_b1,
                      const float* __restrict__ mlp_w2,
                      const float* __restrict__ mlp_b2,
                      const _Float16* __restrict__ fragW16,
                      const _Float16* __restrict__ fragW3,
                      const _Float16* __restrict__ fragDt,
                      const _Float16* __restrict__ fragB2,
                      const unsigned char* __restrict__ emb8,   // may be null
                      float* __restrict__ out,
                      int batch)
{
  __shared__ __align__(16) uint2 Hf8[2][MT * 2 * 64];     // 26624 B fp8(16h) B-frags
  __shared__ float lpr[2][2][SEQP];                       // 3328 B f32 logit partials
  __shared__ int   histL[2][SEQP];                        // 1664
  __shared__ float weights[2][SEQP];                      // 1664
  __shared__ __align__(16) _Float16 t16[2][EMBED];        // 256
  __shared__ __align__(16) _Float16 mi16[2][EMBED];       // 256
  __shared__ __align__(16) _Float16 ip16[2][EMBED];       // 256, pooling partials
  __shared__ float red[16];                               // 64
  // total ~34.1 KB -> 4 blocks/CU

  const int b    = blockIdx.x;
  const int tid  = threadIdx.x;
  const int lane = tid & 63;
  const int wave = tid >> 6;
  const int m    = lane & 15;
  const int quad = lane >> 4;
  const int r    = wave >> 1;            // row within block
  const int w2   = wave & 1;             // wave within row
  const int bA   = 2 * b;
  const int bB   = (2 * b + 1 < batch) ? (2 * b + 1) : (2 * b);

  // ---- phase 0: target embeddings + hist staging (both rows) ----
  if (tid < 2 * EMBED) {
    const int rr = tid >> 6, e = tid & 63;
    t16[rr][e] = (_Float16)item_emb[target_item[rr ? bB : bA] * EMBED + e];
  }
  for (int s = tid; s < 2 * SEQP; s += 256) {
    const int rr = (s >= SEQP) ? 1 : 0;
    const int ss = s - rr * SEQP;
    histL[rr][ss] = (ss < SEQ) ? user_hist[(rr ? bB : bA) * SEQ + ss] : 0;
  }
  __syncthreads();

  // ---- phase 1: gather h -> fp8 B-frag LDS; wave covers its row's kc=w2 half ----
  // slot mapping: st = i (0..12), kc = w2, s = i*16 + m, kb fixed per lane
  const int kb0 = w2 * 32 + quad * 8;
  if (emb8) {
    #pragma unroll
    for (int i = 0; i < MT; ++i) {
      const int s = i * 16 + m;
      uint2 pv = uint2{0u, 0u};
      if (s < SEQ)
        pv = *reinterpret_cast<const uint2*>(&emb8[histL[r][s] * EMBED + kb0]);
      Hf8[r][(i * 2 + w2) * 64 + lane] = pv;
    }
  } else {
    #pragma unroll
    for (int i = 0; i < MT; ++i) {
      const int s = i * 16 + m;
      uint2 pv = uint2{0u, 0u};
      if (s < SEQ) {
        const float4* src = reinterpret_cast<const float4*>(&user_emb[histL[r][s] * EMBED + kb0]);
        const float4 x = src[0], y = src[1];
        int lo = __builtin_amdgcn_cvt_pk_fp8_f32(16.f * x.x, 16.f * x.y, 0, false);
        lo     = __builtin_amdgcn_cvt_pk_fp8_f32(16.f * x.z, 16.f * x.w, lo, true);
        int hi = __builtin_amdgcn_cvt_pk_fp8_f32(16.f * y.x, 16.f * y.y, 0, false);
        hi     = __builtin_amdgcn_cvt_pk_fp8_f32(16.f * y.z, 16.f * y.w, hi, true);
        pv = uint2{(unsigned)lo, (unsigned)hi};
      }
      Hf8[r][(i * 2 + w2) * 64 + lane] = pv;
    }
  }

  // ---- phases 2+3: 2 groups of 4 n-tiles per wave (tiles w2*8 + p*4 + i) ----
  const f16x8 tv0 = *reinterpret_cast<const f16x8*>(&t16[r][quad * 8]);
  const f16x8 tv1 = *reinterpret_cast<const f16x8*>(&t16[r][32 + quad * 8]);
  #pragma unroll 1
  for (int p = 0; p < 2; ++p) {
    long long Aw[4][2];
    f32x4 cn4[4];
    float w2n[4][4];
    #pragma unroll
    for (int i = 0; i < 4; ++i) {
      const int tile = w2 * 8 + p * 4 + i;
      // merged A-frags: fp8( 16*(W0+W2)[k][n] + 16*W3[k][n]*t[k] ), f16 math
      #pragma unroll
      for (int c = 0; c < 2; ++c) {
        const f16x8 w16 = reinterpret_cast<const f16x8*>(fragW16)[(tile * 2 + c) * 64 + lane];
        const f16x8 w3v = reinterpret_cast<const f16x8*>(fragW3)[(tile * 2 + c) * 64 + lane];
        const f16x8 pp = w3v * (c ? tv1 : tv0) + w16;    // v_pk_fma_f16 x4
        int lo = __builtin_amdgcn_cvt_pk_fp8_f32((float)pp[0], (float)pp[1], 0, false);
        lo     = __builtin_amdgcn_cvt_pk_fp8_f32((float)pp[2], (float)pp[3], lo, true);
        int hi = __builtin_amdgcn_cvt_pk_fp8_f32((float)pp[4], (float)pp[5], 0, false);
        hi     = __builtin_amdgcn_cvt_pk_fp8_f32((float)pp[6], (float)pp[7], hi, true);
        Aw[i][c] = __builtin_bit_cast(long long, uint2{(unsigned)lo, (unsigned)hi});
      }
      // c-fold: c[n] = 256*(b1[n] + sum_k t[k] D[k][n])
      const f16x8 d0 = reinterpret_cast<const f16x8*>(fragDt)[(tile * 2 + 0) * 64 + lane];
      const f16x8 d1 = reinterpret_cast<const f16x8*>(fragDt)[(tile * 2 + 1) * 64 + lane];
      const f32x4 z4 = {0.f, 0.f, 0.f, 0.f};
      f32x4 acc = __builtin_amdgcn_mfma_f32_16x16x32_f16(d0, tv0, z4, 0, 0, 0);
      acc = __builtin_amdgcn_mfma_f32_16x16x32_f16(d1, tv1, acc, 0, 0, 0);
      const int nb = tile * 16 + quad * 4;
      const float4 b1v = *reinterpret_cast<const float4*>(&attn_b1[nb]);
      const float4 w2v = *reinterpret_cast<const float4*>(&attn_w2[nb]);
      cn4[i][0] = 256.0f * (b1v.x + acc[0]);
      cn4[i][1] = 256.0f * (b1v.y + acc[1]);
      cn4[i][2] = 256.0f * (b1v.z + acc[2]);
      cn4[i][3] = 256.0f * (b1v.w + acc[3]);
      w2n[i][0] = w2v.x * (1.0f / 256.0f);
      w2n[i][1] = w2v.y * (1.0f / 256.0f);
      w2n[i][2] = w2v.z * (1.0f / 256.0f);
      w2n[i][3] = w2v.w * (1.0f / 256.0f);
    }

    if (p == 0) __syncthreads();   // gather complete; uniform across block

    #pragma unroll 1
    for (int st = 0; st < MT; ++st) {
      const long long b0 = __builtin_bit_cast(long long, Hf8[r][(st * 2 + 0) * 64 + lane]);
      const long long b1 = __builtin_bit_cast(long long, Hf8[r][(st * 2 + 1) * 64 + lane]);
      float lg = 0.f;
      #pragma unroll
      for (int i = 0; i < 4; ++i) {
        f32x4 acc = __builtin_amdgcn_mfma_f32_16x16x32_fp8_fp8(Aw[i][0], b0, cn4[i], 0, 0, 0);
        acc = __builtin_amdgcn_mfma_f32_16x16x32_fp8_fp8(Aw[i][1], b1, acc, 0, 0, 0);
        lg += fmaxf(acc[0], 0.0f) * w2n[i][0] + fmaxf(acc[1], 0.0f) * w2n[i][1]
            + fmaxf(acc[2], 0.0f) * w2n[i][2] + fmaxf(acc[3], 0.0f) * w2n[i][3];
      }
      lg += __shfl_xor(lg, 16, 64);
      lg += __shfl_xor(lg, 32, 64);
      if (lane < 16) {
        if (p == 0) lpr[r][w2][st * 16 + lane] = lg;
        else        lpr[r][w2][st * 16 + lane] += lg;   // same lane: no race
      }
    }
  }
  __syncthreads();

  // ---- phase 4: softmax; each row by its 2 waves, 2 positions per lane ----
  const int pos1 = w2 * 64 + lane;          // 0..127  (< SEQ always)
  const int pos2 = 128 + pos1;              // 128..255
  const float v1 = lpr[r][0][pos1] + lpr[r][1][pos1];
  const float v2 = (pos2 < SEQ) ? (lpr[r][0][pos2] + lpr[r][1][pos2]) : -INFINITY;
  {
    float mx = fmaxf(v1, v2);
    #pragma unroll
    for (int off = 32; off; off >>= 1) mx = fmaxf(mx, __shfl_xor(mx, off, 64));
    if (lane == 0) red[wave] = mx;
  }
  __syncthreads();
  float e1, e2;
  {
    const float mx = fmaxf(red[2 * r], red[2 * r + 1]);
    e1 = expf(v1 - mx);
    e2 = (pos2 < SEQ) ? expf(v2 - mx) : 0.0f;
    float ssum = e1 + e2;
    #pragma unroll
    for (int off = 32; off; off >>= 1) ssum += __shfl_xor(ssum, off, 64);
    if (lane == 0) red[4 + wave] = ssum;
  }
  __syncthreads();
  {
    const float tot = red[4 + 2 * r] + red[4 + 2 * r + 1];
    weights[r][pos1] = e1 / tot;
    if (pos2 < SEQP) weights[r][pos2] = (pos2 < SEQ) ? e2 / tot : 0.0f;
  }
  __syncthreads();

  // ---- phase 5: weighted pooling; wave (r, kc=w2), all 13 st ----
  {
    float pk[8];
    #pragma unroll
    for (int j = 0; j < 8; ++j) pk[j] = 0.f;
    #pragma unroll
    for (int st = 0; st < MT; ++st) {
      const float wt = weights[r][st * 16 + m];
      const uint2 hv = Hf8[r][(st * 2 + w2) * 64 + lane];
      const f32x2 f0 = __builtin_amdgcn_cvt_pk_f32_fp8((int)hv.x, false);
      const f32x2 f1 = __builtin_amdgcn_cvt_pk_f32_fp8((int)hv.x, true);
      const f32x2 f2 = __builtin_amdgcn_cvt_pk_f32_fp8((int)hv.y, false);
      const f32x2 f3 = __builtin_amdgcn_cvt_pk_f32_fp8((int)hv.y, true);
      pk[0] += wt * f0.x;  pk[1] += wt * f0.y;
      pk[2] += wt * f1.x;  pk[3] += wt * f1.y;
      pk[4] += wt * f2.x;  pk[5] += wt * f2.y;
      pk[6] += wt * f3.x;  pk[7] += wt * f3.y;
    }
    // packed-f16 m-dim reduce (4 regs x 4 rounds)
    f16x2 hh[4];
    #pragma unroll
    for (int k = 0; k < 4; ++k)
      hh[k] = __builtin_bit_cast(f16x2, __builtin_amdgcn_cvt_pkrtz(pk[2 * k], pk[2 * k + 1]));
    #pragma unroll
    for (int off = 1; off <= 8; off <<= 1) {
      #pragma unroll
      for (int k = 0; k < 4; ++k)
        hh[k] += __builtin_bit_cast(f16x2, __shfl_xor(__builtin_bit_cast(int, hh[k]), off, 64));
    }
    if (m == 0) {
      #pragma unroll
      for (int k = 0; k < 4; ++k)
        *reinterpret_cast<f16x2*>(&ip16[r][w2 * 32 + quad * 8 + 2 * k]) = hh[k];
    }
  }
  __syncthreads();
  if (tid < 2 * EMBED) {
    const int rr = tid >> 6, e = tid & 63;
    mi16[rr][e] = (_Float16)((float)ip16[rr][e] * 0.0625f);
  }
  __syncthreads();

  // ---- phase 6: prediction head; wave (r, w2) does 8 n-tiles ----
  {
    const f16x8 mb0 = *reinterpret_cast<const f16x8*>(&mi16[r][quad * 8]);
    const f16x8 mb1 = *reinterpret_cast<const f16x8*>(&mi16[r][32 + quad * 8]);
    float z = 0.f;
    #pragma unroll 4
    for (int j = 0; j < 8; ++j) {
      const int tt = w2 * 8 + j;
      const f16x8* B2 = reinterpret_cast<const f16x8*>(fragB2) + (tt * 4) * 64 + lane;
      const int nb = tt * 16 + quad * 4;
      const float4 bb = *reinterpret_cast<const float4*>(&mlp_b1[nb]);
      const float4 ww = *reinterpret_cast<const float4*>(&mlp_w2[nb]);
      f32x4 acc = {bb.x, bb.y, bb.z, bb.w};
      acc = __builtin_amdgcn_mfma_f32_16x16x32_f16(B2[0],   mb0, acc, 0, 0, 0);
      acc = __builtin_amdgcn_mfma_f32_16x16x32_f16(B2[64],  mb1, acc, 0, 0, 0);
      acc = __builtin_amdgcn_mfma_f32_16x16x32_f16(B2[128], tv0, acc, 0, 0, 0);
      acc = __builtin_amdgcn_mfma_f32_16x16x32_f16(B2[192], tv1, acc, 0, 0, 0);
      z += fmaxf(acc[0], 0.0f) * ww.x;
      z += fmaxf(acc[1], 0.0f) * ww.y;
      z += fmaxf(acc[2], 0.0f) * ww.z;
      z += fmaxf(acc[3], 0.0f) * ww.w;
    }
    z += __shfl_xor(z, 16, 64);
    z += __shfl_xor(z, 32, 64);
    if (lane == 0) red[8 + wave] = z;
  }
  __syncthreads();
  if (tid == 0)
    out[bA] = 1.0f / (1.0f + expf(-(red[8] + red[9] + mlp_b2[0])));
  else if (tid == 128 && 2 * b + 1 < batch)
    out[2 * b + 1] = 1.0f / (1.0f + expf(-(red[10] + red[11] + mlp_b2[0])));
}

extern "C" void kernel_launch(void* const* d_in, const int* in_sizes, int n_in,
                              void* d_out, int out_size, void* d_ws, size_t ws_size,
                              hipStream_t stream) {
  const int*   user_hist   = (const int*)  d_in[0];
  const int*   target_item = (const int*)  d_in[1];
  const float* user_emb    = (const float*)d_in[2];
  const float* item_emb    = (const float*)d_in[3];
  const float* attn_w1     = (const float*)d_in[4];
  const float* attn_b1     = (const float*)d_in[5];
  const float* attn_w2     = (const float*)d_in[6];
  // d_in[7] = attn_b2: constant shift on logits -> cancels in softmax
  const float* mlp_w1      = (const float*)d_in[8];
  const float* mlp_b1      = (const float*)d_in[9];
  const float* mlp_w2      = (const float*)d_in[10];
  const float* mlp_b2      = (const float*)d_in[11];
  float* out = (float*)d_out;

  _Float16* fragW16 = (_Float16*)d_ws;                       // 32 KB
  _Float16* fragW3  = (_Float16*)((char*)d_ws + 32768);      // 32 KB
  _Float16* fragDt  = (_Float16*)((char*)d_ws + 65536);      // 32 KB
  _Float16* fragB2  = (_Float16*)((char*)d_ws + 98304);      // 64 KB
  const size_t emb8_off   = 163840;
  const size_t emb8_bytes = (size_t)VOCAB * EMBED;           // 6.4 MB
  unsigned char* emb8 = nullptr;
  if (ws_size >= emb8_off + emb8_bytes)                      // ws_size call-invariant: capture-safe
    emb8 = (unsigned char*)d_ws + emb8_off;

  const int setup_gids   = 10240 + VOCAB * EMBED / 8;
  const int setup_blocks = (setup_gids + 255) / 256;
  din_setup<<<setup_blocks, 256, 0, stream>>>(
      attn_w1, mlp_w1, user_emb, fragW16, fragW3, fragDt, fragB2,
      emb8 ? emb8 : (unsigned char*)d_ws, emb8 ? 1 : 0);

  const int batch = in_sizes[1];
  din_fused_kernel<<<(batch + 1) / 2, 256, 0, stream>>>(
      user_hist, target_item, user_emb, item_emb,
      attn_b1, attn_w2, mlp_b1, mlp_w2, mlp_b2,
      fragW16, fragW3, fragDt, fragB2, emb8, out, batch);
}

// Round 13
// 167.558 us; speedup vs baseline: 1.0477x; 1.0477x over previous
//
#include <hip/hip_runtime.h>
#include <math.h>

#define EMBED   64
#define HIDDEN  256
#define SEQ     200
#define SEQP    208          // padded to 13 s-tiles of 16
#define MT      13
#define VOCAB   100000

typedef _Float16 f16x8  __attribute__((ext_vector_type(8)));
typedef _Float16 f16x2  __attribute__((ext_vector_type(2)));
typedef float    f32x4  __attribute__((ext_vector_type(4)));
typedef float    f32x2  __attribute__((ext_vector_type(2)));

// ---------------- ws layout ----------------
// [0   , 32K ) fragW16: f16 16*(W0+W2)  [tile 16][kc 2][lane 64] x f16x8
// [32K , 64K ) fragW3 : f16 16*W3       [tile 16][kc 2][lane 64] x f16x8
// [64K , 96K ) fragDt : f16 (W1-W2)^T   [tile 16][kc 2][lane 64] x f16x8
// [96K , 160K) fragB2 : f16 mlp_w1      [tile 16][kc 4][lane 64] x f16x8
// [160K, 160K+6.4M) emb8: fp8(16*user_emb), 64 B/vocab row (L3-resident)
//
// FINAL SESSION LEDGER (all measured on MI355X):
//  - BEST (this kernel, R18/R21): 73-75 us fused / ~165 us total.
//    VALU 54% / MFMA 19% / HBM 5% / occ 37% / WRITE 128 KB / conflicts 0.
//  - Register wall: any DIN-row pipeline holding more than this kernel's
//    per-phase live set (~60 arch-VGPRs) spills to scratch; spill cost always
//    exceeded structural gain (R13/R14 seq-2-row, R16 (256,6), R19 f16-frags,
//    R20 wave-per-row, R22 wave-disjoint-2-row; WRITE_SIZE is the canary).
//  - Occupancy is NOT the lever: 53% occ (R15) == 37% occ (R18) == ~74 us.
//  - VALU micro-opts are neutral: the kernel re-equilibrates at ~73-75 us.
//  - ws is re-poisoned per launch: cross-launch setup caching impossible (R17).
//  - Grid-wide single-line completion atomics cost ~100 us (R17).
//  - fp8 A-frags (8 B) over f16 (16 B): same MFMA rate, half the registers.
//  - ~92 us of total-fused gap is setup kernel (~15 us) + fixed harness overhead.

__global__ void din_setup(const float* __restrict__ attn_w1,
                          const float* __restrict__ mlp_w1,
                          const float* __restrict__ user_emb,
                          _Float16* __restrict__ fragW16,
                          _Float16* __restrict__ fragW3,
                          _Float16* __restrict__ fragDt,
                          _Float16* __restrict__ fragB2,
                          unsigned char* __restrict__ emb8,
                          int do_emb) {
  const int gid = blockIdx.x * 256 + threadIdx.x;
  if (gid < 2048) {                                 // fragW16: f16 16*(W0+W2)
    const int i = gid >> 7, rem = gid & 127, kc = rem >> 6, lane = rem & 63;
    const int n = i * 16 + (lane & 15);
    const int kb = kc * 32 + (lane >> 4) * 8;
    #pragma unroll
    for (int j = 0; j < 8; ++j)
      fragW16[gid * 8 + j] = (_Float16)(16.0f * (attn_w1[(kb + j) * HIDDEN + n]
                                               + attn_w1[(128 + kb + j) * HIDDEN + n]));
  } else if (gid < 4096) {                          // fragW3: f16 16*W3
    const int g = gid - 2048;
    const int i = g >> 7, rem = g & 127, kc = rem >> 6, lane = rem & 63;
    const int n = i * 16 + (lane & 15);
    const int kb = kc * 32 + (lane >> 4) * 8;
    #pragma unroll
    for (int j = 0; j < 8; ++j)
      fragW3[g * 8 + j] = (_Float16)(16.0f * attn_w1[(192 + kb + j) * HIDDEN + n]);
  } else if (gid < 6144) {                          // fragDt: f16 (W1-W2)^T A-frags
    const int g = gid - 4096;
    const int i = g >> 7, rem = g & 127, kc = rem >> 6, lane = rem & 63;
    const int n = i * 16 + (lane & 15);
    const int kb = kc * 32 + (lane >> 4) * 8;
    #pragma unroll
    for (int j = 0; j < 8; ++j)
      fragDt[g * 8 + j] = (_Float16)(attn_w1[(64 + kb + j) * HIDDEN + n]
                                   - attn_w1[(128 + kb + j) * HIDDEN + n]);
  } else if (gid < 10240) {                         // fragB2: mlp_w1 f16 A-frags
    const int g = gid - 6144;
    const int nt = g >> 8, kc = (g >> 6) & 3, lane = g & 63;
    const int n = nt * 16 + (lane & 15);
    const int kb = kc * 32 + (lane >> 4) * 8;
    #pragma unroll
    for (int j = 0; j < 8; ++j)
      fragB2[g * 8 + j] = (_Float16)mlp_w1[(kb + j) * HIDDEN + n];
  } else if (do_emb) {                              // emb8: fp8(16*user_emb)
    const int g = gid - 10240;                      // [0, 800000)
    if (g < VOCAB * EMBED / 8) {
      const int base = g * 8;
      const float4 x = *reinterpret_cast<const float4*>(&user_emb[base]);
      const float4 y = *reinterpret_cast<const float4*>(&user_emb[base + 4]);
      int lo = __builtin_amdgcn_cvt_pk_fp8_f32(16.f * x.x, 16.f * x.y, 0, false);
      lo     = __builtin_amdgcn_cvt_pk_fp8_f32(16.f * x.z, 16.f * x.w, lo, true);
      int hi = __builtin_amdgcn_cvt_pk_fp8_f32(16.f * y.x, 16.f * y.y, 0, false);
      hi     = __builtin_amdgcn_cvt_pk_fp8_f32(16.f * y.z, 16.f * y.w, hi, true);
      *reinterpret_cast<uint2*>(&emb8[base]) = uint2{(unsigned)lo, (unsigned)hi};
    }
  }
}

// ---------------- fused kernel: one block (256 thr, 4 waves) per row ----------------
// R18 structure (verified best, reproduced twice):
//  - single-pass 4-tile-per-wave fp8 K=64 GEMM, cn4 as MFMA C-operand
//  - fp8 A-frag merge via f16 pk_fma + cvt chain (8 B frags keep regs low)
//  - conflict-free shfl + f32 lp[4][SEQP] logit path
//  - packed-f16 pooling reduce; strength-reduced gather addressing
//  - launch_bounds(256,4): 128-reg budget; canary WRITE_SIZE >= 1 MB => spill
__global__ __launch_bounds__(256, 4)
void din_fused_kernel(const int* __restrict__ user_hist,
                      const int* __restrict__ target_item,
                      const float* __restrict__ user_emb,
                      const float* __restrict__ item_emb,
                      const float* __restrict__ attn_b1,
                      const float* __restrict__ attn_w2,
                      const float* __restrict__ mlp_b1,
                      const float* __restrict__ mlp_w2,
                      const float* __restrict__ mlp_b2,
                      const _Float16* __restrict__ fragW16,
                      const _Float16* __restrict__ fragW3,
                      const _Float16* __restrict__ fragDt,
                      const _Float16* __restrict__ fragB2,
                      const unsigned char* __restrict__ emb8,   // may be null
                      float* __restrict__ out)
{
  __shared__ __align__(16) uint2 Hf8[MT * 2 * 64];        // 13312 B fp8(16h) B-frags
  __shared__ float lp[4][SEQP];                           // 3328 B f32 logit partials
  __shared__ int   histL[SEQP];                           // 832
  __shared__ float weights[SEQP];                         // 832
  __shared__ __align__(16) _Float16 t16[EMBED];           // 128
  __shared__ __align__(16) _Float16 mi16[EMBED];          // 128
  __shared__ __align__(16) _Float16 ip16[2 * EMBED];      // 256, pooling partials
  __shared__ float red[8];                                // 32
  // total ~18.8 KB

  const int b    = blockIdx.x;
  const int tid  = threadIdx.x;
  const int lane = tid & 63;
  const int wave = tid >> 6;
  const int m    = lane & 15;
  const int quad = lane >> 4;

  // ---- phase 0: target embedding + hist staging ----
  if (tid < EMBED) t16[tid] = (_Float16)item_emb[target_item[b] * EMBED + tid];
  if (tid < SEQP) histL[tid] = (tid < SEQ) ? user_hist[b * SEQ + tid] : 0;
  __syncthreads();

  // ---- phase 1: gather h -> fp8 B-frag LDS; strength-reduced addressing ----
  const int s0  = (wave >> 1) * 16 + m;
  const int kb0 = (wave & 1) * 32 + quad * 8;
  if (emb8) {
    #pragma unroll
    for (int i = 0; i < 7; ++i) {
      const int s = s0 + 32 * i;
      if (s < SEQP) {
        uint2 pv = uint2{0u, 0u};
        if (s < SEQ)
          pv = *reinterpret_cast<const uint2*>(&emb8[histL[s] * EMBED + kb0]);
        Hf8[tid + 256 * i] = pv;
      }
    }
  } else {
    #pragma unroll
    for (int i = 0; i < 7; ++i) {
      const int s = s0 + 32 * i;
      if (s < SEQP) {
        uint2 pv = uint2{0u, 0u};
        if (s < SEQ) {
          const float4* src = reinterpret_cast<const float4*>(&user_emb[histL[s] * EMBED + kb0]);
          const float4 x = src[0], y = src[1];
          int lo = __builtin_amdgcn_cvt_pk_fp8_f32(16.f * x.x, 16.f * x.y, 0, false);
          lo     = __builtin_amdgcn_cvt_pk_fp8_f32(16.f * x.z, 16.f * x.w, lo, true);
          int hi = __builtin_amdgcn_cvt_pk_fp8_f32(16.f * y.x, 16.f * y.y, 0, false);
          hi     = __builtin_amdgcn_cvt_pk_fp8_f32(16.f * y.z, 16.f * y.w, hi, true);
          pv = uint2{(unsigned)lo, (unsigned)hi};
        }
        Hf8[tid + 256 * i] = pv;
      }
    }
  }

  // ---- phase 2: merge + c-fold for this wave's 4 n-tiles (overlaps gather drain) ----
  long long Aw[4][2];
  f32x4 cn4[4];
  float w2n[4][4];
  {
    const f16x8 tv0 = *reinterpret_cast<const f16x8*>(&t16[quad * 8]);
    const f16x8 tv1 = *reinterpret_cast<const f16x8*>(&t16[32 + quad * 8]);
    #pragma unroll
    for (int i = 0; i < 4; ++i) {
      const int tile = wave * 4 + i;
      // merged A-frags: fp8( 16*(W0+W2)[k][n] + 16*W3[k][n]*t[k] ), f16 math
      #pragma unroll
      for (int c = 0; c < 2; ++c) {
        const f16x8 w16 = reinterpret_cast<const f16x8*>(fragW16)[(tile * 2 + c) * 64 + lane];
        const f16x8 w3v = reinterpret_cast<const f16x8*>(fragW3)[(tile * 2 + c) * 64 + lane];
        const f16x8 p = w3v * (c ? tv1 : tv0) + w16;     // v_pk_fma_f16 x4
        int lo = __builtin_amdgcn_cvt_pk_fp8_f32((float)p[0], (float)p[1], 0, false);
        lo     = __builtin_amdgcn_cvt_pk_fp8_f32((float)p[2], (float)p[3], lo, true);
        int hi = __builtin_amdgcn_cvt_pk_fp8_f32((float)p[4], (float)p[5], 0, false);
        hi     = __builtin_amdgcn_cvt_pk_fp8_f32((float)p[6], (float)p[7], hi, true);
        Aw[i][c] = __builtin_bit_cast(long long, uint2{(unsigned)lo, (unsigned)hi});
      }
      // c-fold: c[n] = 256*(b1[n] + sum_k t[k] D[k][n])
      const f16x8 d0 = reinterpret_cast<const f16x8*>(fragDt)[(tile * 2 + 0) * 64 + lane];
      const f16x8 d1 = reinterpret_cast<const f16x8*>(fragDt)[(tile * 2 + 1) * 64 + lane];
      const f32x4 z = {0.f, 0.f, 0.f, 0.f};
      f32x4 acc = __builtin_amdgcn_mfma_f32_16x16x32_f16(d0, tv0, z, 0, 0, 0);
      acc = __builtin_amdgcn_mfma_f32_16x16x32_f16(d1, tv1, acc, 0, 0, 0);
      const int nb = tile * 16 + quad * 4;
      const float4 b1v = *reinterpret_cast<const float4*>(&attn_b1[nb]);
      const float4 w2v = *reinterpret_cast<const float4*>(&attn_w2[nb]);
      cn4[i][0] = 256.0f * (b1v.x + acc[0]);
      cn4[i][1] = 256.0f * (b1v.y + acc[1]);
      cn4[i][2] = 256.0f * (b1v.z + acc[2]);
      cn4[i][3] = 256.0f * (b1v.w + acc[3]);
      w2n[i][0] = w2v.x * (1.0f / 256.0f);
      w2n[i][1] = w2v.y * (1.0f / 256.0f);
      w2n[i][2] = w2v.z * (1.0f / 256.0f);
      w2n[i][3] = w2v.w * (1.0f / 256.0f);
    }
  }
  __syncthreads();   // gather complete before Hf8 reads

  // ---- phase 3: single-pass fp8 K=64 GEMM over 13 s-tiles, 4 n-tiles/wave ----
  #pragma unroll 1
  for (int st = 0; st < MT; ++st) {
    const long long b0 = __builtin_bit_cast(long long, Hf8[(st * 2 + 0) * 64 + lane]);
    const long long b1 = __builtin_bit_cast(long long, Hf8[(st * 2 + 1) * 64 + lane]);
    float lg = 0.f;
    #pragma unroll
    for (int i = 0; i < 4; ++i) {
      f32x4 acc = __builtin_amdgcn_mfma_f32_16x16x32_fp8_fp8(Aw[i][0], b0, cn4[i], 0, 0, 0);
      acc = __builtin_amdgcn_mfma_f32_16x16x32_fp8_fp8(Aw[i][1], b1, acc, 0, 0, 0);
      lg += fmaxf(acc[0], 0.0f) * w2n[i][0] + fmaxf(acc[1], 0.0f) * w2n[i][1]
          + fmaxf(acc[2], 0.0f) * w2n[i][2] + fmaxf(acc[3], 0.0f) * w2n[i][3];
    }
    lg += __shfl_xor(lg, 16, 64);
    lg += __shfl_xor(lg, 32, 64);
    if (lane < 16) lp[wave][st * 16 + lane] = lg;      // conflict-free
  }
  __syncthreads();

  // ---- phase 4: softmax over SEQ ----
  float v = -INFINITY, e = 0.0f;
  if (tid < SEQ)
    v = lp[0][tid] + lp[1][tid] + lp[2][tid] + lp[3][tid];
  {
    float mx = v;
    #pragma unroll
    for (int off = 32; off; off >>= 1) mx = fmaxf(mx, __shfl_xor(mx, off, 64));
    if (lane == 0) red[wave] = mx;
  }
  __syncthreads();
  {
    const float mx = fmaxf(fmaxf(red[0], red[1]), fmaxf(red[2], red[3]));
    e = (tid < SEQ) ? expf(v - mx) : 0.0f;
    float ssum = e;
    #pragma unroll
    for (int off = 32; off; off >>= 1) ssum += __shfl_xor(ssum, off, 64);
    if (lane == 0) red[4 + wave] = ssum;
  }
  __syncthreads();
  {
    const float tot = red[4] + red[5] + red[6] + red[7];
    if (tid < SEQP) weights[tid] = (tid < SEQ) ? e / tot : 0.0f;
  }
  __syncthreads();

  // ---- phase 5: weighted interest pooling; wave -> (kc = w&1, g2 = w>>1) ----
  {
    const int kc = wave & 1, g2 = wave >> 1;
    float pk[8];
    #pragma unroll
    for (int j = 0; j < 8; ++j) pk[j] = 0.f;
    #pragma unroll
    for (int st2 = 0; st2 < 7; ++st2) {
      const int st = g2 + 2 * st2;
      if (st < MT) {
        const float wt = weights[st * 16 + m];
        const uint2 hv = Hf8[(st * 2 + kc) * 64 + lane];
        const f32x2 f0 = __builtin_amdgcn_cvt_pk_f32_fp8((int)hv.x, false);
        const f32x2 f1 = __builtin_amdgcn_cvt_pk_f32_fp8((int)hv.x, true);
        const f32x2 f2 = __builtin_amdgcn_cvt_pk_f32_fp8((int)hv.y, false);
        const f32x2 f3 = __builtin_amdgcn_cvt_pk_f32_fp8((int)hv.y, true);
        pk[0] += wt * f0.x;  pk[1] += wt * f0.y;
        pk[2] += wt * f1.x;  pk[3] += wt * f1.y;
        pk[4] += wt * f2.x;  pk[5] += wt * f2.y;
        pk[6] += wt * f3.x;  pk[7] += wt * f3.y;
      }
    }
    // packed-f16 m-dim reduce (4 regs x 4 rounds)
    f16x2 hh[4];
    #pragma unroll
    for (int k = 0; k < 4; ++k)
      hh[k] = __builtin_bit_cast(f16x2, __builtin_amdgcn_cvt_pkrtz(pk[2 * k], pk[2 * k + 1]));
    #pragma unroll
    for (int off = 1; off <= 8; off <<= 1) {
      #pragma unroll
      for (int k = 0; k < 4; ++k)
        hh[k] += __builtin_bit_cast(f16x2, __shfl_xor(__builtin_bit_cast(int, hh[k]), off, 64));
    }
    if (m == 0) {
      #pragma unroll
      for (int k = 0; k < 4; ++k)
        *reinterpret_cast<f16x2*>(&ip16[g2 * 64 + kc * 32 + quad * 8 + 2 * k]) = hh[k];
    }
  }
  __syncthreads();
  if (tid < EMBED)
    mi16[tid] = (_Float16)(((float)ip16[tid] + (float)ip16[64 + tid]) * 0.0625f);
  __syncthreads();

  // ---- phase 6: prediction head, f16 MFMA; 4 n-tiles/wave ----
  {
    const f16x8 mb0 = *reinterpret_cast<const f16x8*>(&mi16[quad * 8]);
    const f16x8 mb1 = *reinterpret_cast<const f16x8*>(&mi16[32 + quad * 8]);
    const f16x8 tw0 = *reinterpret_cast<const f16x8*>(&t16[quad * 8]);
    const f16x8 tw1 = *reinterpret_cast<const f16x8*>(&t16[32 + quad * 8]);
    float z = 0.f;
    #pragma unroll
    for (int i = 0; i < 4; ++i) {
      const int tt = wave * 4 + i;
      const f16x8* B2 = reinterpret_cast<const f16x8*>(fragB2) + (tt * 4) * 64 + lane;
      const int nb = tt * 16 + quad * 4;
      const float4 bb = *reinterpret_cast<const float4*>(&mlp_b1[nb]);
      const float4 ww = *reinterpret_cast<const float4*>(&mlp_w2[nb]);
      f32x4 acc = {bb.x, bb.y, bb.z, bb.w};
      acc = __builtin_amdgcn_mfma_f32_16x16x32_f16(B2[0],   mb0, acc, 0, 0, 0);
      acc = __builtin_amdgcn_mfma_f32_16x16x32_f16(B2[64],  mb1, acc, 0, 0, 0);
      acc = __builtin_amdgcn_mfma_f32_16x16x32_f16(B2[128], tw0, acc, 0, 0, 0);
      acc = __builtin_amdgcn_mfma_f32_16x16x32_f16(B2[192], tw1, acc, 0, 0, 0);
      z += fmaxf(acc[0], 0.0f) * ww.x;
      z += fmaxf(acc[1], 0.0f) * ww.y;
      z += fmaxf(acc[2], 0.0f) * ww.z;
      z += fmaxf(acc[3], 0.0f) * ww.w;
    }
    z += __shfl_xor(z, 16, 64);
    z += __shfl_xor(z, 32, 64);
    if (lane == 0) red[wave] = z;
  }
  __syncthreads();
  if (tid == 0) {
    const float zz = red[0] + red[1] + red[2] + red[3] + mlp_b2[0];
    out[b] = 1.0f / (1.0f + expf(-zz));
  }
}

extern "C" void kernel_launch(void* const* d_in, const int* in_sizes, int n_in,
                              void* d_out, int out_size, void* d_ws, size_t ws_size,
                              hipStream_t stream) {
  const int*   user_hist   = (const int*)  d_in[0];
  const int*   target_item = (const int*)  d_in[1];
  const float* user_emb    = (const float*)d_in[2];
  const float* item_emb    = (const float*)d_in[3];
  const float* attn_w1     = (const float*)d_in[4];
  const float* attn_b1     = (const float*)d_in[5];
  const float* attn_w2     = (const float*)d_in[6];
  // d_in[7] = attn_b2: constant shift on logits -> cancels in softmax
  const float* mlp_w1      = (const float*)d_in[8];
  const float* mlp_b1      = (const float*)d_in[9];
  const float* mlp_w2      = (const float*)d_in[10];
  const float* mlp_b2      = (const float*)d_in[11];
  float* out = (float*)d_out;

  _Float16* fragW16 = (_Float16*)d_ws;                       // 32 KB
  _Float16* fragW3  = (_Float16*)((char*)d_ws + 32768);      // 32 KB
  _Float16* fragDt  = (_Float16*)((char*)d_ws + 65536);      // 32 KB
  _Float16* fragB2  = (_Float16*)((char*)d_ws + 98304);      // 64 KB
  const size_t emb8_off   = 163840;
  const size_t emb8_bytes = (size_t)VOCAB * EMBED;           // 6.4 MB
  unsigned char* emb8 = nullptr;
  if (ws_size >= emb8_off + emb8_bytes)                      // ws_size call-invariant: capture-safe
    emb8 = (unsigned char*)d_ws + emb8_off;

  const int setup_gids   = 10240 + VOCAB * EMBED / 8;
  const int setup_blocks = (setup_gids + 255) / 256;
  din_setup<<<setup_blocks, 256, 0, stream>>>(
      attn_w1, mlp_w1, user_emb, fragW16, fragW3, fragDt, fragB2,
      emb8 ? emb8 : (unsigned char*)d_ws, emb8 ? 1 : 0);

  const int batch = in_sizes[1];
  din_fused_kernel<<<batch, 256, 0, stream>>>(
      user_hist, target_item, user_emb, item_emb,
      attn_b1, attn_w2, mlp_b1, mlp_w2, mlp_b2,
      fragW16, fragW3, fragDt, fragB2, emb8, out);
}